// Round 1
// baseline (332.074 us; speedup 1.0000x reference)
//
#include <hip/hip_runtime.h>

typedef _Float16 half_t;
typedef __attribute__((ext_vector_type(2))) _Float16 halfx2;
typedef __attribute__((ext_vector_type(8))) _Float16 halfx8;
typedef __attribute__((ext_vector_type(4))) float floatx4;

#define N_NODES 200000
#define N_EDGES 800000
#define NPOS    16384     // 128*128 feature-map positions
#define KIN     484       // 480 backbone + 4 seg channels
#define HID     128

// ws layout
#define WS_DEG   0          // 200000 * u32 = 800000 B
#define WS_MAXD  800000     // 4 B
#define WS_W2H   800064     // 128*128 fp16 = 32768 B
#define WS_U     833536     // 16384*128 fp16 = 4 MiB  (total ~5.03 MB)

// ---------------------------------------------------------------- degree
__global__ __launch_bounds__(256) void k_degree(const int* __restrict__ e,
                                                unsigned* __restrict__ deg) {
  int i4 = (blockIdx.x * 256 + threadIdx.x) * 4;
  if (i4 + 3 < 2 * N_EDGES) {
    int4 v = *(const int4*)(e + i4);
    atomicAdd(&deg[v.x], 1u);
    atomicAdd(&deg[v.y], 1u);
    atomicAdd(&deg[v.z], 1u);
    atomicAdd(&deg[v.w], 1u);
  }
}

// ---------------------------------------------------------------- prep
// blocks [0,256):  U[pos][j] = sum_k W1[j][2+k] * feat[k][pos]   (fp16 MFMA)
// block  256:      W2 -> fp16
// blocks [257,289): max(degree) -> atomicMax
__global__ __launch_bounds__(256) void k_prep(const float* __restrict__ W1,
                                              const float* __restrict__ bb,
                                              const float* __restrict__ seg,
                                              const float* __restrict__ W2,
                                              const unsigned* __restrict__ deg,
                                              unsigned* __restrict__ maxd,
                                              half_t* __restrict__ w2h,
                                              half_t* __restrict__ U) {
  __shared__ half_t Al[128 * 40];   // A chunk [m=j][k], stride 40 (pad 8)
  __shared__ half_t Bl[64 * 40];    // B chunk [n=pos][k], stride 40
  __shared__ half_t Ol[64 * 136];   // out tile [n][j], stride 136

  const int tid = threadIdx.x;
  const int bid = blockIdx.x;

  if (bid < 256) {
    const int n0 = bid * 64;
    const int wave = tid >> 6, lane = tid & 63;
    const int l15 = lane & 15, q8 = (lane >> 4) * 8;

    floatx4 acc[2][4];
    for (int mt = 0; mt < 2; ++mt)
      for (int nt = 0; nt < 4; ++nt)
        acc[mt][nt] = (floatx4){0.f, 0.f, 0.f, 0.f};

    for (int kb = 0; kb < 512; kb += 32) {
      // stage A chunk: thread -> (m = tid>>1, 16 consecutive k)
      {
        int m = tid >> 1, ks = (tid & 1) * 16;
        const float* row = W1 + m * 488;
        for (int i = 0; i < 16; ++i) {
          int k = kb + ks + i;
          float v = (k < KIN) ? row[2 + k] : 0.f;
          Al[m * 40 + ks + i] = (half_t)v;
        }
      }
      // stage B chunk transposed: thread -> (kk = tid>>3, 8 consecutive n)
      {
        int kk = tid >> 3, nc = (tid & 7) * 8;
        int k = kb + kk;
        float vals[8];
        if (k < 480) {
          const float* src = bb + k * NPOS + n0 + nc;
          float4 a = *(const float4*)(src);
          float4 b = *(const float4*)(src + 4);
          vals[0] = a.x; vals[1] = a.y; vals[2] = a.z; vals[3] = a.w;
          vals[4] = b.x; vals[5] = b.y; vals[6] = b.z; vals[7] = b.w;
        } else if (k < KIN) {
          const float* src = seg + (k - 480) * NPOS + n0 + nc;
          float4 a = *(const float4*)(src);
          float4 b = *(const float4*)(src + 4);
          vals[0] = a.x; vals[1] = a.y; vals[2] = a.z; vals[3] = a.w;
          vals[4] = b.x; vals[5] = b.y; vals[6] = b.z; vals[7] = b.w;
        } else {
          for (int i = 0; i < 8; ++i) vals[i] = 0.f;
        }
        for (int i = 0; i < 8; ++i) Bl[(nc + i) * 40 + kk] = (half_t)vals[i];
      }
      __syncthreads();

      halfx8 af[2], bf[4];
      for (int mt = 0; mt < 2; ++mt)
        af[mt] = *(const halfx8*)&Al[(wave * 32 + mt * 16 + l15) * 40 + q8];
      for (int nt = 0; nt < 4; ++nt)
        bf[nt] = *(const halfx8*)&Bl[(nt * 16 + l15) * 40 + q8];
      for (int mt = 0; mt < 2; ++mt)
        for (int nt = 0; nt < 4; ++nt)
          acc[mt][nt] = __builtin_amdgcn_mfma_f32_16x16x32_f16(af[mt], bf[nt],
                                                               acc[mt][nt], 0, 0, 0);
      __syncthreads();
    }

    // transpose through LDS, then coalesced fp16 store
    for (int mt = 0; mt < 2; ++mt)
      for (int nt = 0; nt < 4; ++nt)
        for (int r = 0; r < 4; ++r) {
          int j = wave * 32 + mt * 16 + (lane >> 4) * 4 + r;
          int n = nt * 16 + l15;
          Ol[n * 136 + j] = (half_t)acc[mt][nt][r];
        }
    __syncthreads();
    for (int it = 0; it < 4; ++it) {
      int idx = tid + it * 256;            // 0..1023
      int n = idx >> 4, c8 = (idx & 15) * 8;
      *(halfx8*)(U + (long)(n0 + n) * 128 + c8) = *(const halfx8*)&Ol[n * 136 + c8];
    }
  } else if (bid == 256) {
    for (int i = tid; i < 128 * 128; i += 256) w2h[i] = (half_t)W2[i];
  } else {
    unsigned m = 0;
    for (int i = (bid - 257) * 256 + tid; i < N_NODES; i += 32 * 256)
      m = max(m, deg[i]);
    for (int off = 32; off > 0; off >>= 1) {
      unsigned o = __shfl_down(m, off);
      m = max(m, o);
    }
    if ((tid & 63) == 0) atomicMax(maxd, m);
  }
}

// ---------------------------------------------------------------- main fused
// 64 nodes/block. Phase A: h1 tile (fp16) in LDS from U corner-gathers.
// Phase B: MFMA vs LDS-staged W2, fused bias+relu+store.
__global__ __launch_bounds__(256) void k_main(const float* __restrict__ vertices,
                                              const float* __restrict__ W1,
                                              const float* __restrict__ b1,
                                              const float* __restrict__ b2,
                                              const unsigned* __restrict__ deg,
                                              const unsigned* __restrict__ maxd,
                                              const half_t* __restrict__ U,
                                              const half_t* __restrict__ w2h,
                                              float* __restrict__ out) {
  __shared__ half_t At[64 * 136];    // h1 tile [node][j], stride 136 (pad 8)
  __shared__ half_t W2l[128 * 136];  // W2 [jout][k], stride 136
  __shared__ int   pPos[64];
  __shared__ float pW[4][64];
  __shared__ float pE[4][64];        // cx, cy, deg_norm, dist
  __shared__ float b2l[128];

  const int tid = threadIdx.x;
  const int nodeBase = blockIdx.x * 64;

  // stage W2 (vectorized 16B)
  for (int it = 0; it < 8; ++it) {
    int idx = tid + it * 256;          // 0..2047, 8 halfs each
    int r = idx >> 4, c8 = (idx & 15) * 8;
    *(halfx8*)&W2l[r * 136 + c8] = *(const halfx8*)&w2h[r * 128 + c8];
  }
  if (tid < 128) b2l[tid] = b2[tid];

  // per-node params
  if (tid < 64) {
    int n = nodeBase + tid;
    float vx = vertices[2 * n], vy = vertices[2 * n + 1];
    float ix = vx * (127.0f / 512.0f), iy = vy * (127.0f / 512.0f);
    float fx = floorf(ix), fy = floorf(iy);
    float wx = ix - fx, wy = iy - fy;
    int x0 = min(max((int)fx, 0), 127);
    int y0 = min(max((int)fy, 0), 127);
    pPos[tid] = y0 * 128 + x0;
    pW[0][tid] = (1.f - wx) * (1.f - wy);
    pW[1][tid] = wx * (1.f - wy);
    pW[2][tid] = (1.f - wx) * wy;
    pW[3][tid] = wx * wy;
    pE[0][tid] = vx * (1.f / 512.f);
    pE[1][tid] = vy * (1.f / 512.f);
    float md = (float)(*maxd) + 1e-6f;
    pE[2][tid] = (float)deg[n] / md;
    float dx = fminf(vx, 512.f - vx), dy = fminf(vy, 512.f - vy);
    pE[3][tid] = fminf(dx, dy) * (1.f / 256.f);
  }

  // per-thread W1 scalar-feature columns (j pair = 2*jp, 2*jp+1)
  const int jp = tid & 63, q = tid >> 6;
  const int j2 = jp * 2;
  const float* r0 = W1 + j2 * 488;
  const float* r1 = r0 + 488;
  float c00 = r0[0], c01 = r0[1], c06 = r0[486], c07 = r0[487];
  float c10 = r1[0], c11 = r1[1], c16 = r1[486], c17 = r1[487];
  float bb0 = b1[j2], bb1 = b1[j2 + 1];
  __syncthreads();

  // ---- phase A: z1 = b1 + W1_scalarcols . extras + sum_r w_r * U[pos_r][:]
  for (int it = 0; it < 16; ++it) {
    int ln = it * 4 + q;                       // wave-uniform node
    int pos = pPos[ln];
    float w00 = pW[0][ln], w01 = pW[1][ln], w10 = pW[2][ln], w11 = pW[3][ln];
    float cx = pE[0][ln], cy = pE[1][ln], dn = pE[2][ln], db = pE[3][ln];
    const half_t* base = U + (long)pos * 128 + j2;
    halfx2 u00 = *(const halfx2*)(base);
    halfx2 u01 = *(const halfx2*)(base + 128);
    halfx2 u10 = *(const halfx2*)(base + 16384);
    halfx2 u11 = *(const halfx2*)(base + 16512);
    float z0 = bb0 + c00 * cx + c01 * cy + c06 * dn + c07 * db
             + w00 * (float)u00.x + w01 * (float)u01.x
             + w10 * (float)u10.x + w11 * (float)u11.x;
    float z1 = bb1 + c10 * cx + c11 * cy + c16 * dn + c17 * db
             + w00 * (float)u00.y + w01 * (float)u01.y
             + w10 * (float)u10.y + w11 * (float)u11.y;
    halfx2 h;
    h.x = (half_t)fmaxf(z0, 0.f);
    h.y = (half_t)fmaxf(z1, 0.f);
    *(halfx2*)&At[ln * 136 + j2] = h;
  }
  __syncthreads();

  // ---- phase B: h2 = relu(h1 @ W2^T + b2), MFMA 16x16x32 f16
  const int wave = tid >> 6, lane = tid & 63;
  const int l15 = lane & 15, q4 = lane >> 4;
  floatx4 acc[8];
  for (int t = 0; t < 8; ++t) acc[t] = (floatx4){0.f, 0.f, 0.f, 0.f};

  for (int ks = 0; ks < 128; ks += 32) {
    halfx8 af = *(const halfx8*)&At[(wave * 16 + l15) * 136 + ks + q4 * 8];
    for (int t = 0; t < 8; ++t) {
      halfx8 bf = *(const halfx8*)&W2l[(t * 16 + l15) * 136 + ks + q4 * 8];
      acc[t] = __builtin_amdgcn_mfma_f32_16x16x32_f16(af, bf, acc[t], 0, 0, 0);
    }
  }

  for (int t = 0; t < 8; ++t) {
    int col = t * 16 + l15;
    float bias = b2l[col];
    int row0 = nodeBase + wave * 16 + q4 * 4;
    for (int r = 0; r < 4; ++r)
      out[(long)(row0 + r) * 128 + col] = fmaxf(acc[t][r] + bias, 0.f);
  }
}

// ---------------------------------------------------------------- launch
extern "C" void kernel_launch(void* const* d_in, const int* in_sizes, int n_in,
                              void* d_out, int out_size, void* d_ws, size_t ws_size,
                              hipStream_t stream) {
  const float* vertices = (const float*)d_in[0];
  const float* bb       = (const float*)d_in[1];
  const float* seg      = (const float*)d_in[2];
  const int*   edges    = (const int*)d_in[3];
  const float* W1       = (const float*)d_in[4];
  const float* b1       = (const float*)d_in[5];
  const float* W2       = (const float*)d_in[6];
  const float* b2       = (const float*)d_in[7];
  // d_in[8] = image_size (always 512 per setup_inputs)

  char* ws = (char*)d_ws;
  unsigned* deg  = (unsigned*)(ws + WS_DEG);
  unsigned* maxd = (unsigned*)(ws + WS_MAXD);
  half_t*   w2h  = (half_t*)(ws + WS_W2H);
  half_t*   U    = (half_t*)(ws + WS_U);
  float*    out  = (float*)d_out;

  hipMemsetAsync(ws, 0, 800064, stream);                       // deg + maxd
  k_degree<<<(2 * N_EDGES / 4 + 255) / 256, 256, 0, stream>>>(edges, deg);
  k_prep<<<289, 256, 0, stream>>>(W1, bb, seg, W2, deg, maxd, w2h, U);
  k_main<<<3125, 256, 0, stream>>>(vertices, W1, b1, b2, deg, maxd, U, w2h, out);
}

// Round 5
// 300.614 us; speedup vs baseline: 1.1047x; 1.1047x over previous
//
#include <hip/hip_runtime.h>

typedef _Float16 half_t;
typedef __attribute__((ext_vector_type(2))) _Float16 halfx2;
typedef __attribute__((ext_vector_type(8))) _Float16 halfx8;
typedef __attribute__((ext_vector_type(4))) float floatx4;

#define N_NODES 200000
#define N_EDGES 800000
#define NPOS    16384     // 128*128 feature-map positions
#define KIN     484       // 480 backbone + 4 seg channels

// ws layout (bytes)
#define WS_DEG   0          // 200000 * u32 = 800000
#define WS_MAXD  800000     // 4 (padded to 64)
#define WS_W2H   800064     // 128*128 fp16 = 32768
#define WS_W1H   832832     // 128*512 fp16 = 131072
#define WS_U     963904     // 16384*128 fp16 = 4 MiB (end ~5.16 MB)

// ---------------------------------------------------------------- k_pre
// blocks [0,1563):   degree atomics (round-1 k_degree body)
// block  1563:       W2 -> fp16
// blocks [1564,1692): W1 feature cols -> fp16 [j][k512], one block per j
__global__ __launch_bounds__(256) void k_pre(const int* __restrict__ e,
                                             const float* __restrict__ W1,
                                             const float* __restrict__ W2,
                                             unsigned* __restrict__ deg,
                                             half_t* __restrict__ w2h,
                                             half_t* __restrict__ w1h) {
  const int tid = threadIdx.x, bid = blockIdx.x;
  if (bid < 1563) {
    int i4 = (bid * 256 + tid) * 4;
    if (i4 + 3 < 2 * N_EDGES) {
      int4 v = *(const int4*)(e + i4);
      atomicAdd(&deg[v.x], 1u);
      atomicAdd(&deg[v.y], 1u);
      atomicAdd(&deg[v.z], 1u);
      atomicAdd(&deg[v.w], 1u);
    }
  } else if (bid == 1563) {
    for (int i = tid; i < 128 * 128; i += 256) w2h[i] = (half_t)W2[i];
  } else {
    int j = bid - 1564;                       // one block per j row
    const float* row = W1 + j * 488 + 2;      // feature cols start at 2
    int k1 = tid, k2 = tid + 256;
    w1h[j * 512 + k1] = (half_t)((k1 < KIN) ? row[k1] : 0.f);
    w1h[j * 512 + k2] = (half_t)((k2 < KIN) ? row[k2] : 0.f);
  }
}

// ---------------------------------------------------------------- k_prep
// Round-1 text with ONE delta: A-fragments are two 16B global loads from
// precomputed w1h (bit-identical values to round-1's Al staging, which also
// converted the same W1 floats to fp16). Al LDS + its 256 scalar
// loads/thread deleted. Everything else byte-identical.
// blocks [256,288): max(degree) -> atomicMax
__global__ __launch_bounds__(256) void k_prep(const half_t* __restrict__ w1h,
                                              const float* __restrict__ bb,
                                              const float* __restrict__ seg,
                                              const unsigned* __restrict__ deg,
                                              unsigned* __restrict__ maxd,
                                              half_t* __restrict__ U) {
  __shared__ half_t Bl[64 * 40];    // B chunk [n=pos][k], stride 40
  __shared__ half_t Ol[64 * 136];   // out tile [n][j], stride 136

  const int tid = threadIdx.x;
  const int bid = blockIdx.x;

  if (bid < 256) {
    const int n0 = bid * 64;
    const int wave = tid >> 6, lane = tid & 63;
    const int l15 = lane & 15, q8 = (lane >> 4) * 8;

    floatx4 acc[2][4];
    for (int mt = 0; mt < 2; ++mt)
      for (int nt = 0; nt < 4; ++nt)
        acc[mt][nt] = (floatx4){0.f, 0.f, 0.f, 0.f};

    for (int kb = 0; kb < 512; kb += 32) {
      // A-fragments direct from global w1h (the single delta vs round 1)
      halfx8 af[2];
      for (int mt = 0; mt < 2; ++mt)
        af[mt] = *(const halfx8*)&w1h[(wave * 32 + mt * 16 + l15) * 512 + kb + q8];

      // stage B chunk transposed (round-1 verbatim)
      {
        int kk = tid >> 3, nc = (tid & 7) * 8;
        int k = kb + kk;
        float vals[8];
        if (k < 480) {
          const float* src = bb + k * NPOS + n0 + nc;
          float4 a = *(const float4*)(src);
          float4 b = *(const float4*)(src + 4);
          vals[0] = a.x; vals[1] = a.y; vals[2] = a.z; vals[3] = a.w;
          vals[4] = b.x; vals[5] = b.y; vals[6] = b.z; vals[7] = b.w;
        } else if (k < KIN) {
          const float* src = seg + (k - 480) * NPOS + n0 + nc;
          float4 a = *(const float4*)(src);
          float4 b = *(const float4*)(src + 4);
          vals[0] = a.x; vals[1] = a.y; vals[2] = a.z; vals[3] = a.w;
          vals[4] = b.x; vals[5] = b.y; vals[6] = b.z; vals[7] = b.w;
        } else {
          for (int i = 0; i < 8; ++i) vals[i] = 0.f;
        }
        for (int i = 0; i < 8; ++i) Bl[(nc + i) * 40 + kk] = (half_t)vals[i];
      }
      __syncthreads();

      halfx8 bf[4];
      for (int nt = 0; nt < 4; ++nt)
        bf[nt] = *(const halfx8*)&Bl[(nt * 16 + l15) * 40 + q8];
      for (int mt = 0; mt < 2; ++mt)
        for (int nt = 0; nt < 4; ++nt)
          acc[mt][nt] = __builtin_amdgcn_mfma_f32_16x16x32_f16(af[mt], bf[nt],
                                                               acc[mt][nt], 0, 0, 0);
      __syncthreads();
    }

    // transpose through LDS, then coalesced fp16 store (round-1 verbatim)
    for (int mt = 0; mt < 2; ++mt)
      for (int nt = 0; nt < 4; ++nt)
        for (int r = 0; r < 4; ++r) {
          int j = wave * 32 + mt * 16 + (lane >> 4) * 4 + r;
          int n = nt * 16 + l15;
          Ol[n * 136 + j] = (half_t)acc[mt][nt][r];
        }
    __syncthreads();
    for (int it = 0; it < 4; ++it) {
      int idx = tid + it * 256;            // 0..1023
      int n = idx >> 4, c8 = (idx & 15) * 8;
      *(halfx8*)(U + (long)(n0 + n) * 128 + c8) = *(const halfx8*)&Ol[n * 136 + c8];
    }
  } else {
    unsigned m = 0;
    for (int i = (bid - 256) * 256 + tid; i < N_NODES; i += 32 * 256)
      m = max(m, deg[i]);
    for (int off = 32; off > 0; off >>= 1) {
      unsigned o = __shfl_down(m, off);
      m = max(m, o);
    }
    if ((tid & 63) == 0) atomicMax(maxd, m);
  }
}

// ---------------------------------------------------------------- k_main
// ROUND-1 BYTE-IDENTICAL (the passing version). h1 round-trips through LDS.
__global__ __launch_bounds__(256) void k_main(const float* __restrict__ vertices,
                                              const float* __restrict__ W1,
                                              const float* __restrict__ b1,
                                              const float* __restrict__ b2,
                                              const unsigned* __restrict__ deg,
                                              const unsigned* __restrict__ maxd,
                                              const half_t* __restrict__ U,
                                              const half_t* __restrict__ w2h,
                                              float* __restrict__ out) {
  __shared__ half_t At[64 * 136];    // h1 tile [node][j], stride 136 (pad 8)
  __shared__ half_t W2l[128 * 136];  // W2 [jout][k], stride 136
  __shared__ int   pPos[64];
  __shared__ float pW[4][64];
  __shared__ float pE[4][64];        // cx, cy, deg_norm, dist
  __shared__ float b2l[128];

  const int tid = threadIdx.x;
  const int nodeBase = blockIdx.x * 64;

  // stage W2 (vectorized 16B)
  for (int it = 0; it < 8; ++it) {
    int idx = tid + it * 256;          // 0..2047, 8 halfs each
    int r = idx >> 4, c8 = (idx & 15) * 8;
    *(halfx8*)&W2l[r * 136 + c8] = *(const halfx8*)&w2h[r * 128 + c8];
  }
  if (tid < 128) b2l[tid] = b2[tid];

  // per-node params
  if (tid < 64) {
    int n = nodeBase + tid;
    float vx = vertices[2 * n], vy = vertices[2 * n + 1];
    float ix = vx * (127.0f / 512.0f), iy = vy * (127.0f / 512.0f);
    float fx = floorf(ix), fy = floorf(iy);
    float wx = ix - fx, wy = iy - fy;
    int x0 = min(max((int)fx, 0), 127);
    int y0 = min(max((int)fy, 0), 127);
    pPos[tid] = y0 * 128 + x0;
    pW[0][tid] = (1.f - wx) * (1.f - wy);
    pW[1][tid] = wx * (1.f - wy);
    pW[2][tid] = (1.f - wx) * wy;
    pW[3][tid] = wx * wy;
    pE[0][tid] = vx * (1.f / 512.f);
    pE[1][tid] = vy * (1.f / 512.f);
    float md = (float)(*maxd) + 1e-6f;
    pE[2][tid] = (float)deg[n] / md;
    float dx = fminf(vx, 512.f - vx), dy = fminf(vy, 512.f - vy);
    pE[3][tid] = fminf(dx, dy) * (1.f / 256.f);
  }

  // per-thread W1 scalar-feature columns (j pair = 2*jp, 2*jp+1)
  const int jp = tid & 63, q = tid >> 6;
  const int j2 = jp * 2;
  const float* r0 = W1 + j2 * 488;
  const float* r1 = r0 + 488;
  float c00 = r0[0], c01 = r0[1], c06 = r0[486], c07 = r0[487];
  float c10 = r1[0], c11 = r1[1], c16 = r1[486], c17 = r1[487];
  float bb0 = b1[j2], bb1 = b1[j2 + 1];
  __syncthreads();

  // ---- phase A: z1 = b1 + W1_scalarcols . extras + sum_r w_r * U[pos_r][:]
  for (int it = 0; it < 16; ++it) {
    int ln = it * 4 + q;                       // wave-uniform node
    int pos = pPos[ln];
    float w00 = pW[0][ln], w01 = pW[1][ln], w10 = pW[2][ln], w11 = pW[3][ln];
    float cx = pE[0][ln], cy = pE[1][ln], dn = pE[2][ln], db = pE[3][ln];
    const half_t* base = U + (long)pos * 128 + j2;
    halfx2 u00 = *(const halfx2*)(base);
    halfx2 u01 = *(const halfx2*)(base + 128);
    halfx2 u10 = *(const halfx2*)(base + 16384);
    halfx2 u11 = *(const halfx2*)(base + 16512);
    float z0 = bb0 + c00 * cx + c01 * cy + c06 * dn + c07 * db
             + w00 * (float)u00.x + w01 * (float)u01.x
             + w10 * (float)u10.x + w11 * (float)u11.x;
    float z1 = bb1 + c10 * cx + c11 * cy + c16 * dn + c17 * db
             + w00 * (float)u00.y + w01 * (float)u01.y
             + w10 * (float)u10.y + w11 * (float)u11.y;
    halfx2 h;
    h.x = (half_t)fmaxf(z0, 0.f);
    h.y = (half_t)fmaxf(z1, 0.f);
    *(halfx2*)&At[ln * 136 + j2] = h;
  }
  __syncthreads();

  // ---- phase B: h2 = relu(h1 @ W2^T + b2), MFMA 16x16x32 f16
  const int wave = tid >> 6, lane = tid & 63;
  const int l15 = lane & 15, q4 = lane >> 4;
  floatx4 acc[8];
  for (int t = 0; t < 8; ++t) acc[t] = (floatx4){0.f, 0.f, 0.f, 0.f};

  for (int ks = 0; ks < 128; ks += 32) {
    halfx8 af = *(const halfx8*)&At[(wave * 16 + l15) * 136 + ks + q4 * 8];
    for (int t = 0; t < 8; ++t) {
      halfx8 bf = *(const halfx8*)&W2l[(t * 16 + l15) * 136 + ks + q4 * 8];
      acc[t] = __builtin_amdgcn_mfma_f32_16x16x32_f16(af, bf, acc[t], 0, 0, 0);
    }
  }

  for (int t = 0; t < 8; ++t) {
    int col = t * 16 + l15;
    float bias = b2l[col];
    int row0 = nodeBase + wave * 16 + q4 * 4;
    for (int r = 0; r < 4; ++r)
      out[(long)(row0 + r) * 128 + col] = fmaxf(acc[t][r] + bias, 0.f);
  }
}

// ---------------------------------------------------------------- launch
extern "C" void kernel_launch(void* const* d_in, const int* in_sizes, int n_in,
                              void* d_out, int out_size, void* d_ws, size_t ws_size,
                              hipStream_t stream) {
  const float* vertices = (const float*)d_in[0];
  const float* bb       = (const float*)d_in[1];
  const float* seg      = (const float*)d_in[2];
  const int*   edges    = (const int*)d_in[3];
  const float* W1       = (const float*)d_in[4];
  const float* b1       = (const float*)d_in[5];
  const float* W2       = (const float*)d_in[6];
  const float* b2       = (const float*)d_in[7];

  char* ws = (char*)d_ws;
  unsigned* deg  = (unsigned*)(ws + WS_DEG);
  unsigned* maxd = (unsigned*)(ws + WS_MAXD);
  half_t*   w2h  = (half_t*)(ws + WS_W2H);
  half_t*   w1h  = (half_t*)(ws + WS_W1H);
  half_t*   U    = (half_t*)(ws + WS_U);
  float*    outp = (float*)d_out;

  hipMemsetAsync(ws, 0, 800064, stream);   // deg + maxd
  k_pre<<<1692, 256, 0, stream>>>(edges, W1, W2, deg, w2h, w1h);
  k_prep<<<288, 256, 0, stream>>>(w1h, bb, seg, deg, maxd, U);
  k_main<<<3125, 256, 0, stream>>>(vertices, W1, b1, b2, deg, maxd, U, w2h, outp);
}

// Round 6
// 291.833 us; speedup vs baseline: 1.1379x; 1.0301x over previous
//
#include <hip/hip_runtime.h>

typedef _Float16 half_t;
typedef __attribute__((ext_vector_type(2))) _Float16 halfx2;
typedef __attribute__((ext_vector_type(8))) _Float16 halfx8;
typedef __attribute__((ext_vector_type(4))) float floatx4;

#define N_NODES 200000
#define N_EDGES 800000
#define NPOS    16384     // 128*128 feature-map positions
#define KIN     484       // 480 backbone + 4 seg channels

// ws layout (bytes). deg final aliases privatized copy 0.
#define WS_DEGP  0          // 4 * 200000 * u32 = 3,200,000
#define WS_MAXD  3200000    // 64
#define WS_W2H   3200064    // 128*128 fp16 = 32768
#define WS_W1H   3232832    // 128*512 fp16 = 131072
#define WS_U     3363904    // 16384*128 fp16 = 4 MiB (end ~7.56 MB)

// ---------------------------------------------------------------- k0 (tiny)
// bid 0: W2 -> fp16 ; bid 1..128: W1 feature cols -> fp16 [j][k512]
__global__ __launch_bounds__(256) void k0(const float* __restrict__ W1,
                                          const float* __restrict__ W2,
                                          half_t* __restrict__ w2h,
                                          half_t* __restrict__ w1h) {
  const int tid = threadIdx.x, bid = blockIdx.x;
  if (bid == 0) {
    for (int i = tid; i < 128 * 128; i += 256) w2h[i] = (half_t)W2[i];
  } else {
    int j = bid - 1;
    const float* row = W1 + j * 488 + 2;
    int k1 = tid, k2 = tid + 256;
    w1h[j * 512 + k1] = (half_t)((k1 < KIN) ? row[k1] : 0.f);
    w1h[j * 512 + k2] = (half_t)((k2 < KIN) ? row[k2] : 0.f);
  }
}

// ---------------------------------------------------------------- k1
// blocks [0,256):    U-GEMM (round-5 verified body, A-frags from w1h)
// blocks [256,1819): degree atomics into 4 privatized copies (no dependency
//                    on the GEMM blocks — pure occupancy overlap)
__global__ __launch_bounds__(256) void k1(const half_t* __restrict__ w1h,
                                          const float* __restrict__ bb,
                                          const float* __restrict__ seg,
                                          const int* __restrict__ e,
                                          unsigned* __restrict__ degp,
                                          half_t* __restrict__ U) {
  __shared__ half_t Bl[64 * 40];    // B chunk [n=pos][k], stride 40
  __shared__ half_t Ol[64 * 136];   // out tile [n][j], stride 136

  const int tid = threadIdx.x;
  const int bid = blockIdx.x;

  if (bid < 256) {
    const int n0 = bid * 64;
    const int wave = tid >> 6, lane = tid & 63;
    const int l15 = lane & 15, q8 = (lane >> 4) * 8;

    floatx4 acc[2][4];
    for (int mt = 0; mt < 2; ++mt)
      for (int nt = 0; nt < 4; ++nt)
        acc[mt][nt] = (floatx4){0.f, 0.f, 0.f, 0.f};

    for (int kb = 0; kb < 512; kb += 32) {
      halfx8 af[2];
      for (int mt = 0; mt < 2; ++mt)
        af[mt] = *(const halfx8*)&w1h[(wave * 32 + mt * 16 + l15) * 512 + kb + q8];

      {
        int kk = tid >> 3, nc = (tid & 7) * 8;
        int k = kb + kk;
        float vals[8];
        if (k < 480) {
          const float* src = bb + k * NPOS + n0 + nc;
          float4 a = *(const float4*)(src);
          float4 b = *(const float4*)(src + 4);
          vals[0] = a.x; vals[1] = a.y; vals[2] = a.z; vals[3] = a.w;
          vals[4] = b.x; vals[5] = b.y; vals[6] = b.z; vals[7] = b.w;
        } else if (k < KIN) {
          const float* src = seg + (k - 480) * NPOS + n0 + nc;
          float4 a = *(const float4*)(src);
          float4 b = *(const float4*)(src + 4);
          vals[0] = a.x; vals[1] = a.y; vals[2] = a.z; vals[3] = a.w;
          vals[4] = b.x; vals[5] = b.y; vals[6] = b.z; vals[7] = b.w;
        } else {
          for (int i = 0; i < 8; ++i) vals[i] = 0.f;
        }
        for (int i = 0; i < 8; ++i) Bl[(nc + i) * 40 + kk] = (half_t)vals[i];
      }
      __syncthreads();

      halfx8 bf[4];
      for (int nt = 0; nt < 4; ++nt)
        bf[nt] = *(const halfx8*)&Bl[(nt * 16 + l15) * 40 + q8];
      for (int mt = 0; mt < 2; ++mt)
        for (int nt = 0; nt < 4; ++nt)
          acc[mt][nt] = __builtin_amdgcn_mfma_f32_16x16x32_f16(af[mt], bf[nt],
                                                               acc[mt][nt], 0, 0, 0);
      __syncthreads();
    }

    for (int mt = 0; mt < 2; ++mt)
      for (int nt = 0; nt < 4; ++nt)
        for (int r = 0; r < 4; ++r) {
          int j = wave * 32 + mt * 16 + (lane >> 4) * 4 + r;
          int n = nt * 16 + l15;
          Ol[n * 136 + j] = (half_t)acc[mt][nt][r];
        }
    __syncthreads();
    for (int it = 0; it < 4; ++it) {
      int idx = tid + it * 256;            // 0..1023
      int n = idx >> 4, c8 = (idx & 15) * 8;
      *(halfx8*)(U + (long)(n0 + n) * 128 + c8) = *(const halfx8*)&Ol[n * 136 + c8];
    }
  } else {
    const int b = bid - 256;
    int i4 = (b * 256 + tid) * 4;
    unsigned* dc = degp + (b & 3) * N_NODES;   // privatized copy
    if (i4 + 3 < 2 * N_EDGES) {
      int4 v = *(const int4*)(e + i4);
      atomicAdd(&dc[v.x], 1u);
      atomicAdd(&dc[v.y], 1u);
      atomicAdd(&dc[v.z], 1u);
      atomicAdd(&dc[v.w], 1u);
    }
  }
}

// ---------------------------------------------------------------- k2 (tiny)
// deg[n] = sum of 4 copies (written in place into copy 0); max -> atomicMax
__global__ __launch_bounds__(256) void k2(unsigned* __restrict__ degp,
                                          unsigned* __restrict__ maxd) {
  const int tid = threadIdx.x;
  unsigned m = 0;
  for (int it = 0; it < 4; ++it) {
    int n = blockIdx.x * 1024 + it * 256 + tid;
    if (n < N_NODES) {
      unsigned s = degp[n] + degp[N_NODES + n] + degp[2 * N_NODES + n] +
                   degp[3 * N_NODES + n];
      degp[n] = s;                       // thread-exclusive in-place write
      m = max(m, s);
    }
  }
  for (int off = 32; off > 0; off >>= 1) {
    unsigned o = (unsigned)__shfl_down((int)m, off);
    m = max(m, o);
  }
  if ((tid & 63) == 0) atomicMax(maxd, m);
}

// ---------------------------------------------------------------- k_main
// Phase A = round-5 byte-identical. Phase B: W2 staged in two 64-k halves
// (same MFMA k-order 0,32,64,96 -> bit-identical). LDS 55 -> ~38.7 KB.
__global__ __launch_bounds__(256) void k_main(const float* __restrict__ vertices,
                                              const float* __restrict__ W1,
                                              const float* __restrict__ b1,
                                              const float* __restrict__ b2,
                                              const unsigned* __restrict__ deg,
                                              const unsigned* __restrict__ maxd,
                                              const half_t* __restrict__ U,
                                              const half_t* __restrict__ w2h,
                                              float* __restrict__ out) {
  __shared__ half_t At[64 * 136];    // h1 tile [node][j], stride 136
  __shared__ half_t W2l[128 * 72];   // W2 k-half [jout][64+8]
  __shared__ int   pPos[64];
  __shared__ float pW[4][64];
  __shared__ float pE[4][64];
  __shared__ float b2l[128];

  const int tid = threadIdx.x;
  const int nodeBase = blockIdx.x * 64;

  if (tid < 128) b2l[tid] = b2[tid];

  // per-node params (round-5 verbatim)
  if (tid < 64) {
    int n = nodeBase + tid;
    float vx = vertices[2 * n], vy = vertices[2 * n + 1];
    float ix = vx * (127.0f / 512.0f), iy = vy * (127.0f / 512.0f);
    float fx = floorf(ix), fy = floorf(iy);
    float wx = ix - fx, wy = iy - fy;
    int x0 = min(max((int)fx, 0), 127);
    int y0 = min(max((int)fy, 0), 127);
    pPos[tid] = y0 * 128 + x0;
    pW[0][tid] = (1.f - wx) * (1.f - wy);
    pW[1][tid] = wx * (1.f - wy);
    pW[2][tid] = (1.f - wx) * wy;
    pW[3][tid] = wx * wy;
    pE[0][tid] = vx * (1.f / 512.f);
    pE[1][tid] = vy * (1.f / 512.f);
    float md = (float)(*maxd) + 1e-6f;
    pE[2][tid] = (float)deg[n] / md;
    float dx = fminf(vx, 512.f - vx), dy = fminf(vy, 512.f - vy);
    pE[3][tid] = fminf(dx, dy) * (1.f / 256.f);
  }

  // per-thread W1 scalar-feature columns (round-5 verbatim)
  const int jp = tid & 63, q = tid >> 6;
  const int j2 = jp * 2;
  const float* r0 = W1 + j2 * 488;
  const float* r1 = r0 + 488;
  float c00 = r0[0], c01 = r0[1], c06 = r0[486], c07 = r0[487];
  float c10 = r1[0], c11 = r1[1], c16 = r1[486], c17 = r1[487];
  float bb0 = b1[j2], bb1 = b1[j2 + 1];
  __syncthreads();

  // ---- phase A (round-5 verbatim): h1 -> At via LDS
  for (int it = 0; it < 16; ++it) {
    int ln = it * 4 + q;
    int pos = pPos[ln];
    float w00 = pW[0][ln], w01 = pW[1][ln], w10 = pW[2][ln], w11 = pW[3][ln];
    float cx = pE[0][ln], cy = pE[1][ln], dn = pE[2][ln], db = pE[3][ln];
    const half_t* base = U + (long)pos * 128 + j2;
    halfx2 u00 = *(const halfx2*)(base);
    halfx2 u01 = *(const halfx2*)(base + 128);
    halfx2 u10 = *(const halfx2*)(base + 16384);
    halfx2 u11 = *(const halfx2*)(base + 16512);
    float z0 = bb0 + c00 * cx + c01 * cy + c06 * dn + c07 * db
             + w00 * (float)u00.x + w01 * (float)u01.x
             + w10 * (float)u10.x + w11 * (float)u11.x;
    float z1 = bb1 + c10 * cx + c11 * cy + c16 * dn + c17 * db
             + w00 * (float)u00.y + w01 * (float)u01.y
             + w10 * (float)u10.y + w11 * (float)u11.y;
    halfx2 h;
    h.x = (half_t)fmaxf(z0, 0.f);
    h.y = (half_t)fmaxf(z1, 0.f);
    *(halfx2*)&At[ln * 136 + j2] = h;
  }
  __syncthreads();

  // ---- phase B: two W2 k-halves through one LDS buffer
  const int wave = tid >> 6, lane = tid & 63;
  const int l15 = lane & 15, q4 = lane >> 4;
  floatx4 acc[8];
  for (int t = 0; t < 8; ++t) acc[t] = (floatx4){0.f, 0.f, 0.f, 0.f};

  for (int h = 0; h < 2; ++h) {
    __syncthreads();                       // protect W2l reuse
    for (int it = 0; it < 4; ++it) {
      int idx = tid + it * 256;            // 0..1023
      int r = idx >> 3, c8 = (idx & 7) * 8;
      *(halfx8*)&W2l[r * 72 + c8] = *(const halfx8*)&w2h[r * 128 + h * 64 + c8];
    }
    __syncthreads();
    for (int ks = 0; ks < 64; ks += 32) {
      halfx8 af = *(const halfx8*)&At[(wave * 16 + l15) * 136 + h * 64 + ks + q4 * 8];
      for (int t = 0; t < 8; ++t) {
        halfx8 bf = *(const halfx8*)&W2l[(t * 16 + l15) * 72 + ks + q4 * 8];
        acc[t] = __builtin_amdgcn_mfma_f32_16x16x32_f16(af, bf, acc[t], 0, 0, 0);
      }
    }
  }

  for (int t = 0; t < 8; ++t) {
    int col = t * 16 + l15;
    float bias = b2l[col];
    int row0 = nodeBase + wave * 16 + q4 * 4;
    for (int r = 0; r < 4; ++r)
      out[(long)(row0 + r) * 128 + col] = fmaxf(acc[t][r] + bias, 0.f);
  }
}

// ---------------------------------------------------------------- launch
extern "C" void kernel_launch(void* const* d_in, const int* in_sizes, int n_in,
                              void* d_out, int out_size, void* d_ws, size_t ws_size,
                              hipStream_t stream) {
  const float* vertices = (const float*)d_in[0];
  const float* bb       = (const float*)d_in[1];
  const float* seg      = (const float*)d_in[2];
  const int*   edges    = (const int*)d_in[3];
  const float* W1       = (const float*)d_in[4];
  const float* b1       = (const float*)d_in[5];
  const float* W2       = (const float*)d_in[6];
  const float* b2       = (const float*)d_in[7];

  char* ws = (char*)d_ws;
  unsigned* degp = (unsigned*)(ws + WS_DEGP);
  unsigned* maxd = (unsigned*)(ws + WS_MAXD);
  half_t*   w2h  = (half_t*)(ws + WS_W2H);
  half_t*   w1h  = (half_t*)(ws + WS_W1H);
  half_t*   U    = (half_t*)(ws + WS_U);
  float*    outp = (float*)d_out;

  hipMemsetAsync(ws, 0, 3200064, stream);   // degPriv x4 + maxd
  k0<<<129, 256, 0, stream>>>(W1, W2, w2h, w1h);
  k1<<<256 + 1563, 256, 0, stream>>>(w1h, bb, seg, edges, degp, U);
  k2<<<196, 256, 0, stream>>>(degp, maxd);
  k_main<<<3125, 256, 0, stream>>>(vertices, W1, b1, b2, degp, maxd, U, w2h, outp);
}